// Round 7
// baseline (170.222 us; speedup 1.0000x reference)
//
#include <hip/hip_runtime.h>
#include <hip/hip_bf16.h>
#include <cmath>

// Problem constants
#define BATCH 8
#define NH 8
#define BH 64          // BATCH*NH
#define SEQ 1024
#define DH 64          // head dim
#define NM 64          // modes

// ws layout (floats):
//  P   : [inp 2][tq 8][bh 64][c 2][m 64][d 64] = 8,388,608  (fwd partials)
//  Pr  : [inp 2][bh 64][c 2][m 64][d 64]       = 1,048,576  (reduced)
//  C1c : [bh 64][i 64][q 64][c 2]              =   524,288
//  C2  : [bh 64][j 64][m 64][c 2]              =   524,288
#define P_PLANE 4096   // 64m*64d
#define P_FLOATS (2*8*64*2*4096)
#define PR_OFF   P_FLOATS
#define C1C_OFF  (PR_OFF + 2*64*2*4096)
#define C2_OFF   (C1C_OFF + 64*64*64*2)

// ---------------------------------------------------------------------------
// Kernel 1 (unchanged from R6, control): forward partial DFT with t<->t+512
// symmetry. grid = (bh 64, inp 2, tq 8) = 1024 blocks x 256 thr.
// ---------------------------------------------------------------------------
__global__ __launch_bounds__(256) void k_dft(const float* __restrict__ q,
                                             const float* __restrict__ k,
                                             float* __restrict__ P) {
  const int bid = blockIdx.x;
  const int bh = bid & 63;
  const int inp = (bid >> 6) & 1;
  const int tq = bid >> 7;  // 0..7, 64 t' each
  const float* x = (inp ? k : q) + (size_t)bh * (SEQ * DH);  // [t][d]

  __shared__ float se[64 * 68], so[64 * 68];  // row stride 68
  const int tid = threadIdx.x;
  const int dg = tid & 7;          // 8 d-groups of 8
  const int par = (tid >> 3) & 1;  // t-interleave stream
  const int pg = (tid >> 4) & 1;   // mode parity
  const int mg = tid >> 5;         // 0..7 -> 4 modes each
  const int d0 = dg * 8;

  const int t0g = tq * 64;
  {
    const float4* srcA = reinterpret_cast<const float4*>(x + (size_t)t0g * DH);
    const float4* srcB = reinterpret_cast<const float4*>(x + (size_t)(t0g + 512) * DH);
#pragma unroll
    for (int i = 0; i < 4; ++i) {
      int idx = tid + i * 256;  // t*16 + d4
      int tt = idx >> 4, d4 = (idx & 15) * 4;
      float4 a = srcA[idx], b = srcB[idx];
      *reinterpret_cast<float4*>(&se[tt * 68 + d4]) =
          make_float4(a.x + b.x, a.y + b.y, a.z + b.z, a.w + b.w);
      *reinterpret_cast<float4*>(&so[tt * 68 + d4]) =
          make_float4(a.x - b.x, a.y - b.y, a.z - b.z, a.w - b.w);
    }
  }
  __syncthreads();

  const float* s = pg ? so : se;

  float accr[4][8] = {{0.f}}, acci[4][8] = {{0.f}};
  float stepc[4], steps[4], wr[4], wi[4];
#pragma unroll
  for (int mi = 0; mi < 4; ++mi) {
    const int m = 2 * (mg * 4 + mi) + pg;
    const int ps = (2 * m) & 1023;
    stepc[mi] = cospif((float)ps * (1.0f / 512.0f));
    steps[mi] = -sinpif((float)ps * (1.0f / 512.0f));
    const int p0 = (m * (t0g + par)) & 1023;
    wr[mi] = cospif((float)p0 * (1.0f / 512.0f));
    wi[mi] = -sinpif((float)p0 * (1.0f / 512.0f));
  }

#pragma unroll 4
  for (int k2 = 0; k2 < 32; ++k2) {
    const int tl = 2 * k2 + par;
    float4 a = *reinterpret_cast<const float4*>(&s[tl * 68 + d0]);
    float4 b = *reinterpret_cast<const float4*>(&s[tl * 68 + d0 + 4]);
    float xv[8] = {a.x, a.y, a.z, a.w, b.x, b.y, b.z, b.w};
#pragma unroll
    for (int mi = 0; mi < 4; ++mi) {
      float cwr = wr[mi], cwi = wi[mi];
#pragma unroll
      for (int di = 0; di < 8; ++di) {
        accr[mi][di] = fmaf(cwr, xv[di], accr[mi][di]);
        acci[mi][di] = fmaf(cwi, xv[di], acci[mi][di]);
      }
      float nr = cwr * stepc[mi] - cwi * steps[mi];
      float ni = cwr * steps[mi] + cwi * stepc[mi];
      wr[mi] = nr; wi[mi] = ni;
    }
  }

#pragma unroll
  for (int mi = 0; mi < 4; ++mi) {
#pragma unroll
    for (int di = 0; di < 8; ++di) {
      accr[mi][di] += __shfl_xor(accr[mi][di], 8, 64);
      acci[mi][di] += __shfl_xor(acci[mi][di], 8, 64);
    }
  }

  if (par == 0) {
    const size_t base = (((size_t)inp * 8 + tq) * 64 + bh) * 2 * P_PLANE;
#pragma unroll
    for (int mi = 0; mi < 4; ++mi) {
      const int m = 2 * (mg * 4 + mi) + pg;
      float* pr = P + base + (size_t)m * 64 + d0;
      float* pi = P + base + P_PLANE + (size_t)m * 64 + d0;
      *reinterpret_cast<float4*>(pr) =
          make_float4(accr[mi][0], accr[mi][1], accr[mi][2], accr[mi][3]);
      *reinterpret_cast<float4*>(pr + 4) =
          make_float4(accr[mi][4], accr[mi][5], accr[mi][6], accr[mi][7]);
      *reinterpret_cast<float4*>(pi) =
          make_float4(acci[mi][0], acci[mi][1], acci[mi][2], acci[mi][3]);
      *reinterpret_cast<float4*>(pi + 4) =
          make_float4(acci[mi][4], acci[mi][5], acci[mi][6], acci[mi][7]);
    }
  }
}

// ---------------------------------------------------------------------------
// Kernel 1b (unchanged, control): reduce 8 t-partials -> Pr.
// ---------------------------------------------------------------------------
__global__ __launch_bounds__(256) void k_red(const float* __restrict__ P,
                                             float* __restrict__ Pr) {
  const int idx = blockIdx.x * 256 + threadIdx.x;
  const int inp = idx >> 17;
  const int r = idx & 131071;
  const float4* p4 = reinterpret_cast<const float4*>(P);
  const size_t base = ((size_t)inp * 8) * 131072 + r;
  float4 acc = p4[base];
#pragma unroll
  for (int t = 1; t < 8; ++t) {
    float4 v = p4[base + (size_t)t * 131072];
    acc.x += v.x; acc.y += v.y; acc.z += v.z; acc.w += v.w;
  }
  reinterpret_cast<float4*>(Pr)[idx] = acc;
}

// stable complex tanh
__device__ __forceinline__ void ctanh_f(float x, float y, float& rr, float& ri) {
  float a = 2.0f * x, b = 2.0f * y;
  if (fabsf(a) > 20.0f) {
    rr = (a > 0.0f) ? 1.0f : -1.0f;
    ri = 0.0f;
  } else {
    float ea = expf(a), ena = expf(-a);
    float sb, cb;
    sincosf(b, &sb, &cb);
    float den = 0.5f * (ea + ena) + cb;
    rr = 0.5f * (ea - ena) / den;
    ri = sb / den;
  }
}

// ---------------------------------------------------------------------------
// Kernel 2a: scores -> ctanh -> context -> C1. grid = (bh, q-16th) = 1024
// blocks x 256 thr, ~42 KB LDS -> 3 blocks/CU = 12 waves/CU (was 2 blk, 8 w).
// Scores: thread (q=tid>>6, k=tid&63); C1: thread (q, d=tid&63) -> K reads
// lane-consecutive (conflict-free), A/Q wave-uniform broadcasts.
// ---------------------------------------------------------------------------
__global__ __launch_bounds__(256) void k_mid_a(const float* __restrict__ Pr,
                                               float* __restrict__ C1c) {
  __shared__ float Kr[64][68], Ki[64][68];
  __shared__ float Qr[4][68], Qi[4][68];
  __shared__ float Ar[4][68], Ai[4][68];
  __shared__ float C1rs[64][6], C1is[64][6];

  const int tid = threadIdx.x;
  const int bh = blockIdx.x >> 4;
  const int qo = blockIdx.x & 15;  // 4 q's per block

  // K: Pr[inp=1][bh][c][m][d]
  const float4* kbase = reinterpret_cast<const float4*>(Pr + ((size_t)(64 + bh)) * 8192);
  for (int idx = tid; idx < 1024; idx += 256) {
    int kk = idx >> 4, dd = (idx & 15) * 4;
    float4 vr = kbase[idx];
    float4 vi = kbase[idx + 1024];
    *reinterpret_cast<float4*>(&Kr[kk][dd]) = vr;
    *reinterpret_cast<float4*>(&Ki[kk][dd]) = vi;
  }
  // Q: Pr[inp=0][bh][c][qo*4 .. qo*4+3][d]
  {
    const float4* qbase =
        reinterpret_cast<const float4*>(Pr + (size_t)bh * 8192 + (size_t)qo * 256);
    if (tid < 64) {
      int qi2 = tid >> 4, dd = (tid & 15) * 4;
      float4 vr = qbase[tid];
      float4 vi = qbase[tid + 1024];
      *reinterpret_cast<float4*>(&Qr[qi2][dd]) = vr;
      *reinterpret_cast<float4*>(&Qi[qi2][dd]) = vi;
    }
  }
  __syncthreads();

  // scores S[q][k] = sum_d Q[q][d]*K[k][d] (complex, no conj) -> ctanh
  {
    const int q = tid >> 6, kk = tid & 63;
    float s0 = 0.f, s1 = 0.f;
    for (int d = 0; d < 64; d += 4) {
      const float4 qr = *reinterpret_cast<const float4*>(&Qr[q][d]);
      const float4 qi = *reinterpret_cast<const float4*>(&Qi[q][d]);
      const float4 kr = *reinterpret_cast<const float4*>(&Kr[kk][d]);
      const float4 ki = *reinterpret_cast<const float4*>(&Ki[kk][d]);
      s0 = fmaf(qr.x, kr.x, s0); s0 = fmaf(-qi.x, ki.x, s0);
      s1 = fmaf(qr.x, ki.x, s1); s1 = fmaf(qi.x, kr.x, s1);
      s0 = fmaf(qr.y, kr.y, s0); s0 = fmaf(-qi.y, ki.y, s0);
      s1 = fmaf(qr.y, ki.y, s1); s1 = fmaf(qi.y, kr.y, s1);
      s0 = fmaf(qr.z, kr.z, s0); s0 = fmaf(-qi.z, ki.z, s0);
      s1 = fmaf(qr.z, ki.z, s1); s1 = fmaf(qi.z, kr.z, s1);
      s0 = fmaf(qr.w, kr.w, s0); s0 = fmaf(-qi.w, ki.w, s0);
      s1 = fmaf(qr.w, ki.w, s1); s1 = fmaf(qi.w, kr.w, s1);
    }
    float rr, ri;
    ctanh_f(s0, s1, rr, ri);
    Ar[q][kk] = rr;
    Ai[q][kk] = ri;
  }
  __syncthreads();

  // C1[d][q] = sum_k A[q][k]*K[k][d]; thread (q, d) -> lane-consecutive K
  {
    const int q = tid >> 6, dd = tid & 63;
    float cr = 0.f, ci = 0.f;
#pragma unroll 8
    for (int kk = 0; kk < 64; ++kk) {
      float a_r = Ar[q][kk], a_i = Ai[q][kk];  // broadcast
      float krv = Kr[kk][dd], kiv = Ki[kk][dd];
      cr = fmaf(a_r, krv, cr); cr = fmaf(-a_i, kiv, cr);
      ci = fmaf(a_r, kiv, ci); ci = fmaf(a_i, krv, ci);
    }
    C1rs[dd][q] = cr;
    C1is[dd][q] = ci;
  }
  __syncthreads();

  // write C1c[bh][i][qglobal][2]: 64i x 4q = 256 cells, one per thread
  {
    const int i = tid >> 2, ql = tid & 3;
    size_t o = (((size_t)bh * 64 + i) * 64 + qo * 4 + ql) * 2;
    *reinterpret_cast<float2*>(&C1c[o]) = make_float2(C1rs[i][ql], C1is[i][ql]);
  }
}

// ---------------------------------------------------------------------------
// Kernel 2b: C2[b,h,j,q] = sum_i C1[b,h,i,q] * (wre+i*wim)[h,i,j,q]
// grid = (h 8, j 64, b 8) = 4096 one-wave blocks = 16 waves/CU (was 8).
// lane = q -> w loads 256B coalesced; C1 float2 loads 512B coalesced.
// ---------------------------------------------------------------------------
__global__ __launch_bounds__(64) void k_mid_b(const float* __restrict__ C1c,
                                              const float* __restrict__ wre,
                                              const float* __restrict__ wim,
                                              float* __restrict__ C2) {
  const int bid = blockIdx.x;
  const int j = bid & 63;
  const int h = (bid >> 6) & 7;
  const int b = bid >> 9;        // 0..7
  const int lane = threadIdx.x;  // q

  const int bh = b * 8 + h;
  const float2* c1 = reinterpret_cast<const float2*>(C1c) + (size_t)bh * 4096 + lane;
  const float* wrp = wre + ((size_t)h * 4096 + j) * 64 + lane;
  const float* wip = wim + ((size_t)h * 4096 + j) * 64 + lane;

  float ar = 0.f, ai = 0.f;
#pragma unroll 8
  for (int i = 0; i < 64; ++i) {
    float wr = wrp[(size_t)i * 4096];
    float wi = wip[(size_t)i * 4096];
    float2 c = c1[(size_t)i * 64];
    ar = fmaf(c.x, wr, ar); ar = fmaf(-c.y, wi, ar);
    ai = fmaf(c.x, wi, ai); ai = fmaf(c.y, wr, ai);
  }
  // C2[bh][j][m][2]
  *reinterpret_cast<float2*>(&C2[(((size_t)bh * 64 + j) * 64 + lane) * 2]) =
      make_float2(ar, ai);
}

// ---------------------------------------------------------------------------
// Kernel 3: inverse partial DFT with (-1)^m symmetry. grid = (bh 64, tc 8)
// = 512 blocks x 256 thr. Thread tile 4t' x 4j: per m-step 2 ds_read_b128
// (8 floats) feed 32 fmaf -> port 12.3k cyc/CU (half of R6's 24.5k) and
// issue ~12.3k cyc/SIMD-group -- balanced.
// ---------------------------------------------------------------------------
__global__ __launch_bounds__(256) void k_idft(const float* __restrict__ C2,
                                              float* __restrict__ out) {
  __shared__ float Cr[64][68], Ci[64][68];
  const int tid = threadIdx.x;
  const int bh = blockIdx.x >> 3;
  const int tc = blockIdx.x & 7;
  const float s = 1.0f / (512.0f * 512.0f * 1024.0f);

  for (int idx = tid; idx < 4096; idx += 256) {
    int j = idx >> 6, m = idx & 63;
    float f = (m == 0) ? s : 2.0f * s;
    float2 c = *reinterpret_cast<const float2*>(&C2[(((size_t)bh * 64 + j) * 64 + m) * 2]);
    Cr[m][j] = f * c.x;
    Ci[m][j] = f * c.y;
  }
  __syncthreads();

  const int tg = tid & 15, jg = tid >> 4;
  const int tp0 = tc * 64 + tg * 4;  // 4 consecutive t'
  const int j0 = jg * 4;             // 4 consecutive j

  float sc[4], ss[4], wc[4], wsn[4];
#pragma unroll
  for (int kk = 0; kk < 4; ++kk) {
    float ph = (float)((tp0 + kk) & 1023) * (1.0f / 512.0f);
    sc[kk] = cospif(ph);  // step e^{+2*pi*i*t'/1024} per m
    ss[kk] = sinpif(ph);
    wc[kk] = 1.0f;        // m = 0
    wsn[kk] = 0.0f;
  }

  float accE[4][4] = {{0.f}}, accO[4][4] = {{0.f}};
#pragma unroll 2
  for (int m = 0; m < 64; ++m) {
    float4 c0 = *reinterpret_cast<const float4*>(&Cr[m][j0]);
    float4 e0 = *reinterpret_cast<const float4*>(&Ci[m][j0]);
    float crv[4] = {c0.x, c0.y, c0.z, c0.w};
    float civ[4] = {e0.x, e0.y, e0.z, e0.w};
    float(*acc)[4] = (m & 1) ? accO : accE;
#pragma unroll
    for (int kk = 0; kk < 4; ++kk) {
      float cw = wc[kk], sw = wsn[kk];
#pragma unroll
      for (int jj = 0; jj < 4; ++jj) {
        acc[kk][jj] = fmaf(crv[jj], cw, acc[kk][jj]);
        acc[kk][jj] = fmaf(-civ[jj], sw, acc[kk][jj]);
      }
      float nr = cw * sc[kk] - sw * ss[kk];
      float ni = cw * ss[kk] + sw * sc[kk];
      wc[kk] = nr; wsn[kk] = ni;
    }
  }

  // out[bh][j][t]: float4 at tp0 (E+O) and float4 at tp0+512 (E-O)
#pragma unroll
  for (int jj = 0; jj < 4; ++jj) {
    float* row = &out[((size_t)bh * 64 + j0 + jj) * 1024];
    *reinterpret_cast<float4*>(&row[tp0]) =
        make_float4(accE[0][jj] + accO[0][jj], accE[1][jj] + accO[1][jj],
                    accE[2][jj] + accO[2][jj], accE[3][jj] + accO[3][jj]);
    *reinterpret_cast<float4*>(&row[tp0 + 512]) =
        make_float4(accE[0][jj] - accO[0][jj], accE[1][jj] - accO[1][jj],
                    accE[2][jj] - accO[2][jj], accE[3][jj] - accO[3][jj]);
  }
}

extern "C" void kernel_launch(void* const* d_in, const int* in_sizes, int n_in,
                              void* d_out, int out_size, void* d_ws, size_t ws_size,
                              hipStream_t stream) {
  const float* q   = (const float*)d_in[0];
  const float* k   = (const float*)d_in[1];
  // d_in[2] = value, unused by the reference forward
  const float* wre = (const float*)d_in[3];
  const float* wim = (const float*)d_in[4];
  float* out = (float*)d_out;
  float* ws  = (float*)d_ws;

  float* P   = ws;
  float* Pr  = ws + PR_OFF;
  float* C1c = ws + C1C_OFF;
  float* C2  = ws + C2_OFF;

  k_dft  <<<1024, 256, 0, stream>>>(q, k, P);
  k_red  <<<1024, 256, 0, stream>>>(P, Pr);
  k_mid_a<<<1024, 256, 0, stream>>>(Pr, C1c);
  k_mid_b<<<4096,  64, 0, stream>>>(C1c, wre, wim, C2);
  k_idft <<<512,  256, 0, stream>>>(C2, out);
}

// Round 8
// 160.275 us; speedup vs baseline: 1.0621x; 1.0621x over previous
//
#include <hip/hip_runtime.h>
#include <hip/hip_bf16.h>
#include <cmath>

// Problem constants
#define BATCH 8
#define NH 8
#define BH 64          // BATCH*NH
#define SEQ 1024
#define DH 64          // head dim
#define NM 64          // modes

// ws layout (floats):
//  P   : [inp 2][tq 8][bh 64][c 2][m 64][d 64] = 8,388,608  (fwd partials)
//  Pr  : [inp 2][bh 64][c 2][m 64][d 64]       = 1,048,576  (reduced)
//  C1c : [bh 64][i 64][q 64][c 2]              =   524,288
//  C2  : [bh 64][j 64][m 64][c 2]              =   524,288
#define P_PLANE 4096   // 64m*64d
#define P_FLOATS (2*8*64*2*4096)
#define PR_OFF   P_FLOATS
#define C1C_OFF  (PR_OFF + 2*64*2*4096)
#define C2_OFF   (C1C_OFF + 64*64*64*2)

// ---------------------------------------------------------------------------
// Kernel 1: forward partial DFT with t<->t+512 symmetry.
// grid = (bh 64, inp 2, tq 8) = 1024 blocks x 512 thr.
// LDS 34.8 KB -> 4 blocks/CU = 32 waves/CU = 8 waves/SIMD (R6/R7 had 4).
// Thread: 2 modes (one parity) x 8 d, 2-way t-interleave; VGPR ~60 keeps the
// 8-wave/SIMD VGPR cliff (<=64) satisfied.
// ---------------------------------------------------------------------------
__global__ __launch_bounds__(512) void k_dft(const float* __restrict__ q,
                                             const float* __restrict__ k,
                                             float* __restrict__ P) {
  const int bid = blockIdx.x;
  const int bh = bid & 63;
  const int inp = (bid >> 6) & 1;
  const int tq = bid >> 7;  // 0..7, 64 t' each
  const float* x = (inp ? k : q) + (size_t)bh * (SEQ * DH);  // [t][d]

  __shared__ float se[64 * 68], so[64 * 68];  // row stride 68
  const int tid = threadIdx.x;
  const int dg = tid & 7;          // 8 d-groups of 8
  const int par = (tid >> 3) & 1;  // t-interleave stream
  const int pg = (tid >> 4) & 1;   // mode parity
  const int mg = tid >> 5;         // 0..15 -> 2 modes each
  const int d0 = dg * 8;
  // modes handled: m = 2*(mg*2+mi) + pg, mi in {0,1}

  const int t0g = tq * 64;
  {
    const float4* srcA = reinterpret_cast<const float4*>(x + (size_t)t0g * DH);
    const float4* srcB = reinterpret_cast<const float4*>(x + (size_t)(t0g + 512) * DH);
#pragma unroll
    for (int i = 0; i < 2; ++i) {
      int idx = tid + i * 512;  // t*16 + d4, 1024 float4 total
      int tt = idx >> 4, d4 = (idx & 15) * 4;
      float4 a = srcA[idx], b = srcB[idx];
      *reinterpret_cast<float4*>(&se[tt * 68 + d4]) =
          make_float4(a.x + b.x, a.y + b.y, a.z + b.z, a.w + b.w);
      *reinterpret_cast<float4*>(&so[tt * 68 + d4]) =
          make_float4(a.x - b.x, a.y - b.y, a.z - b.z, a.w - b.w);
    }
  }
  __syncthreads();

  const float* s = pg ? so : se;

  float accr[2][8] = {{0.f}}, acci[2][8] = {{0.f}};
  float stepc[2], steps[2], wr[2], wi[2];
#pragma unroll
  for (int mi = 0; mi < 2; ++mi) {
    const int m = 2 * (mg * 2 + mi) + pg;
    const int ps = (2 * m) & 1023;  // t' advances by 2
    stepc[mi] = cospif((float)ps * (1.0f / 512.0f));
    steps[mi] = -sinpif((float)ps * (1.0f / 512.0f));
    const int p0 = (m * (t0g + par)) & 1023;
    wr[mi] = cospif((float)p0 * (1.0f / 512.0f));
    wi[mi] = -sinpif((float)p0 * (1.0f / 512.0f));
  }

#pragma unroll 4
  for (int k2 = 0; k2 < 32; ++k2) {
    const int tl = 2 * k2 + par;
    float4 a = *reinterpret_cast<const float4*>(&s[tl * 68 + d0]);
    float4 b = *reinterpret_cast<const float4*>(&s[tl * 68 + d0 + 4]);
    float xv[8] = {a.x, a.y, a.z, a.w, b.x, b.y, b.z, b.w};
#pragma unroll
    for (int mi = 0; mi < 2; ++mi) {
      float cwr = wr[mi], cwi = wi[mi];
#pragma unroll
      for (int di = 0; di < 8; ++di) {
        accr[mi][di] = fmaf(cwr, xv[di], accr[mi][di]);
        acci[mi][di] = fmaf(cwi, xv[di], acci[mi][di]);
      }
      float nr = cwr * stepc[mi] - cwi * steps[mi];
      float ni = cwr * steps[mi] + cwi * stepc[mi];
      wr[mi] = nr; wi[mi] = ni;
    }
  }

  // combine par streams (partner lane differs in bit 3)
#pragma unroll
  for (int mi = 0; mi < 2; ++mi) {
#pragma unroll
    for (int di = 0; di < 8; ++di) {
      accr[mi][di] += __shfl_xor(accr[mi][di], 8, 64);
      acci[mi][di] += __shfl_xor(acci[mi][di], 8, 64);
    }
  }

  if (par == 0) {
    const size_t base = (((size_t)inp * 8 + tq) * 64 + bh) * 2 * P_PLANE;
#pragma unroll
    for (int mi = 0; mi < 2; ++mi) {
      const int m = 2 * (mg * 2 + mi) + pg;
      float* pr = P + base + (size_t)m * 64 + d0;
      float* pi = P + base + P_PLANE + (size_t)m * 64 + d0;
      *reinterpret_cast<float4*>(pr) =
          make_float4(accr[mi][0], accr[mi][1], accr[mi][2], accr[mi][3]);
      *reinterpret_cast<float4*>(pr + 4) =
          make_float4(accr[mi][4], accr[mi][5], accr[mi][6], accr[mi][7]);
      *reinterpret_cast<float4*>(pi) =
          make_float4(acci[mi][0], acci[mi][1], acci[mi][2], acci[mi][3]);
      *reinterpret_cast<float4*>(pi + 4) =
          make_float4(acci[mi][4], acci[mi][5], acci[mi][6], acci[mi][7]);
    }
  }
}

// ---------------------------------------------------------------------------
// Kernel 1b (unchanged, control): reduce 8 t-partials -> Pr.
// ---------------------------------------------------------------------------
__global__ __launch_bounds__(256) void k_red(const float* __restrict__ P,
                                             float* __restrict__ Pr) {
  const int idx = blockIdx.x * 256 + threadIdx.x;
  const int inp = idx >> 17;
  const int r = idx & 131071;
  const float4* p4 = reinterpret_cast<const float4*>(P);
  const size_t base = ((size_t)inp * 8) * 131072 + r;
  float4 acc = p4[base];
#pragma unroll
  for (int t = 1; t < 8; ++t) {
    float4 v = p4[base + (size_t)t * 131072];
    acc.x += v.x; acc.y += v.y; acc.z += v.z; acc.w += v.w;
  }
  reinterpret_cast<float4*>(Pr)[idx] = acc;
}

// stable complex tanh
__device__ __forceinline__ void ctanh_f(float x, float y, float& rr, float& ri) {
  float a = 2.0f * x, b = 2.0f * y;
  if (fabsf(a) > 20.0f) {
    rr = (a > 0.0f) ? 1.0f : -1.0f;
    ri = 0.0f;
  } else {
    float ea = expf(a), ena = expf(-a);
    float sb, cb;
    sincosf(b, &sb, &cb);
    float den = 0.5f * (ea + ena) + cb;
    rr = 0.5f * (ea - ena) / den;
    ri = sb / den;
  }
}

// ---------------------------------------------------------------------------
// Kernel 2a: scores -> ctanh -> context -> C1. grid = (bh, q-eighth) = 512
// blocks x 512 thr, ~48 KB LDS -> 3 blocks/CU = 24 waves/CU = 6 waves/SIMD
// (R7: 3/SIMD). Thread maps: scores (q=tid>>6, k=tid&63); C1 (q, d=tid&63).
// ---------------------------------------------------------------------------
__global__ __launch_bounds__(512) void k_mid_a(const float* __restrict__ Pr,
                                               float* __restrict__ C1c) {
  __shared__ float Kr[64][68], Ki[64][68];
  __shared__ float Qr[8][68], Qi[8][68];
  __shared__ float Ar[8][68], Ai[8][68];
  __shared__ float C1rs[64][9], C1is[64][9];

  const int tid = threadIdx.x;
  const int bh = blockIdx.x >> 3;
  const int qo = blockIdx.x & 7;  // 8 q's per block

  // K: Pr[inp=1][bh][c][m][d]
  const float4* kbase = reinterpret_cast<const float4*>(Pr + ((size_t)(64 + bh)) * 8192);
  for (int idx = tid; idx < 1024; idx += 512) {
    int kk = idx >> 4, dd = (idx & 15) * 4;
    float4 vr = kbase[idx];
    float4 vi = kbase[idx + 1024];
    *reinterpret_cast<float4*>(&Kr[kk][dd]) = vr;
    *reinterpret_cast<float4*>(&Ki[kk][dd]) = vi;
  }
  // Q: Pr[inp=0][bh][c][qo*8 .. qo*8+7][d]
  {
    const float4* qbase =
        reinterpret_cast<const float4*>(Pr + (size_t)bh * 8192 + (size_t)qo * 512);
    if (tid < 128) {
      int qi2 = tid >> 4, dd = (tid & 15) * 4;
      float4 vr = qbase[tid];
      float4 vi = qbase[tid + 1024];
      *reinterpret_cast<float4*>(&Qr[qi2][dd]) = vr;
      *reinterpret_cast<float4*>(&Qi[qi2][dd]) = vi;
    }
  }
  __syncthreads();

  // scores S[q][k] = sum_d Q[q][d]*K[k][d] (complex, no conj) -> ctanh
  {
    const int q = tid >> 6, kk = tid & 63;
    float s0 = 0.f, s1 = 0.f;
    for (int d = 0; d < 64; d += 4) {
      const float4 qr = *reinterpret_cast<const float4*>(&Qr[q][d]);
      const float4 qi = *reinterpret_cast<const float4*>(&Qi[q][d]);
      const float4 kr = *reinterpret_cast<const float4*>(&Kr[kk][d]);
      const float4 ki = *reinterpret_cast<const float4*>(&Ki[kk][d]);
      s0 = fmaf(qr.x, kr.x, s0); s0 = fmaf(-qi.x, ki.x, s0);
      s1 = fmaf(qr.x, ki.x, s1); s1 = fmaf(qi.x, kr.x, s1);
      s0 = fmaf(qr.y, kr.y, s0); s0 = fmaf(-qi.y, ki.y, s0);
      s1 = fmaf(qr.y, ki.y, s1); s1 = fmaf(qi.y, kr.y, s1);
      s0 = fmaf(qr.z, kr.z, s0); s0 = fmaf(-qi.z, ki.z, s0);
      s1 = fmaf(qr.z, ki.z, s1); s1 = fmaf(qi.z, kr.z, s1);
      s0 = fmaf(qr.w, kr.w, s0); s0 = fmaf(-qi.w, ki.w, s0);
      s1 = fmaf(qr.w, ki.w, s1); s1 = fmaf(qi.w, kr.w, s1);
    }
    float rr, ri;
    ctanh_f(s0, s1, rr, ri);
    Ar[q][kk] = rr;
    Ai[q][kk] = ri;
  }
  __syncthreads();

  // C1[d][q] = sum_k A[q][k]*K[k][d]; thread (q, d) -> lane-consecutive K
  {
    const int q = tid >> 6, dd = tid & 63;
    float cr = 0.f, ci = 0.f;
#pragma unroll 8
    for (int kk = 0; kk < 64; ++kk) {
      float a_r = Ar[q][kk], a_i = Ai[q][kk];  // broadcast
      float krv = Kr[kk][dd], kiv = Ki[kk][dd];
      cr = fmaf(a_r, krv, cr); cr = fmaf(-a_i, kiv, cr);
      ci = fmaf(a_r, kiv, ci); ci = fmaf(a_i, krv, ci);
    }
    C1rs[dd][q] = cr;
    C1is[dd][q] = ci;
  }
  __syncthreads();

  // write C1c[bh][i][qglobal][2]: 64i x 8q = 512 cells, one per thread
  {
    const int i = tid >> 3, ql = tid & 7;
    size_t o = (((size_t)bh * 64 + i) * 64 + qo * 8 + ql) * 2;
    *reinterpret_cast<float2*>(&C1c[o]) = make_float2(C1rs[i][ql], C1is[i][ql]);
  }
}

// ---------------------------------------------------------------------------
// Kernel 2b (unchanged, control): C2[b,h,j,q] = sum_i C1 * w.
// grid = (h 8, j 64, b 8) = 4096 one-wave blocks.
// ---------------------------------------------------------------------------
__global__ __launch_bounds__(64) void k_mid_b(const float* __restrict__ C1c,
                                              const float* __restrict__ wre,
                                              const float* __restrict__ wim,
                                              float* __restrict__ C2) {
  const int bid = blockIdx.x;
  const int j = bid & 63;
  const int h = (bid >> 6) & 7;
  const int b = bid >> 9;
  const int lane = threadIdx.x;  // q

  const int bh = b * 8 + h;
  const float2* c1 = reinterpret_cast<const float2*>(C1c) + (size_t)bh * 4096 + lane;
  const float* wrp = wre + ((size_t)h * 4096 + j) * 64 + lane;
  const float* wip = wim + ((size_t)h * 4096 + j) * 64 + lane;

  float ar = 0.f, ai = 0.f;
#pragma unroll 8
  for (int i = 0; i < 64; ++i) {
    float wr = wrp[(size_t)i * 4096];
    float wi = wip[(size_t)i * 4096];
    float2 c = c1[(size_t)i * 64];
    ar = fmaf(c.x, wr, ar); ar = fmaf(-c.y, wi, ar);
    ai = fmaf(c.x, wi, ai); ai = fmaf(c.y, wr, ai);
  }
  *reinterpret_cast<float2*>(&C2[(((size_t)bh * 64 + j) * 64 + lane) * 2]) =
      make_float2(ar, ai);
}

// ---------------------------------------------------------------------------
// Kernel 3: inverse partial DFT with (-1)^m symmetry. grid = (bh 64, tc 8,
// jh 2) = 1024 blocks x 256 thr. LDS 18.4 KB (half the j range) -> 4+ resident
// blocks/CU = 16+ waves/CU = 4/SIMD (R7: 2/SIMD). Tile 4t' x 2j: per m-step
// 2 ds_read_b64 (broadcast across t-groups) feed 16 fma + 16 rot.
// ---------------------------------------------------------------------------
__global__ __launch_bounds__(256) void k_idft(const float* __restrict__ C2,
                                              float* __restrict__ out) {
  __shared__ float Cr[64][36], Ci[64][36];
  const int tid = threadIdx.x;
  const int jh = blockIdx.x & 1;
  const int tc = (blockIdx.x >> 1) & 7;
  const int bh = blockIdx.x >> 4;
  const float s = 1.0f / (512.0f * 512.0f * 1024.0f);

  // stage 64 m x 32 j (this block's j-half), scale pre-folded
  for (int idx = tid; idx < 2048; idx += 256) {
    int j = idx >> 6, m = idx & 63;  // j 0..31 local
    int jg_ = jh * 32 + j;
    float f = (m == 0) ? s : 2.0f * s;
    float2 c = *reinterpret_cast<const float2*>(&C2[(((size_t)bh * 64 + jg_) * 64 + m) * 2]);
    Cr[m][j] = f * c.x;
    Ci[m][j] = f * c.y;
  }
  __syncthreads();

  const int tg = tid & 15, jg = tid >> 4;  // tg 16 x 4t', jg 16 x 2j
  const int tp0 = tc * 64 + tg * 4;        // 4 consecutive t'
  const int j0 = jg * 2;                   // 2 consecutive j (local)

  float sc[4], ss[4], wc[4], wsn[4];
#pragma unroll
  for (int kk = 0; kk < 4; ++kk) {
    float ph = (float)((tp0 + kk) & 1023) * (1.0f / 512.0f);
    sc[kk] = cospif(ph);  // step e^{+2*pi*i*t'/1024} per m
    ss[kk] = sinpif(ph);
    wc[kk] = 1.0f;        // m = 0
    wsn[kk] = 0.0f;
  }

  float accE[4][2] = {{0.f}}, accO[4][2] = {{0.f}};
#pragma unroll 4
  for (int m = 0; m < 64; ++m) {
    float2 c0 = *reinterpret_cast<const float2*>(&Cr[m][j0]);
    float2 e0 = *reinterpret_cast<const float2*>(&Ci[m][j0]);
    float crv[2] = {c0.x, c0.y};
    float civ[2] = {e0.x, e0.y};
    float(*acc)[2] = (m & 1) ? accO : accE;
#pragma unroll
    for (int kk = 0; kk < 4; ++kk) {
      float cw = wc[kk], sw = wsn[kk];
#pragma unroll
      for (int jj = 0; jj < 2; ++jj) {
        acc[kk][jj] = fmaf(crv[jj], cw, acc[kk][jj]);
        acc[kk][jj] = fmaf(-civ[jj], sw, acc[kk][jj]);
      }
      float nr = cw * sc[kk] - sw * ss[kk];
      float ni = cw * ss[kk] + sw * sc[kk];
      wc[kk] = nr; wsn[kk] = ni;
    }
  }

  // out[bh][j][t]: float4 at tp0 (E+O) and float4 at tp0+512 (E-O)
#pragma unroll
  for (int jj = 0; jj < 2; ++jj) {
    float* row = &out[((size_t)bh * 64 + jh * 32 + j0 + jj) * 1024];
    *reinterpret_cast<float4*>(&row[tp0]) =
        make_float4(accE[0][jj] + accO[0][jj], accE[1][jj] + accO[1][jj],
                    accE[2][jj] + accO[2][jj], accE[3][jj] + accO[3][jj]);
    *reinterpret_cast<float4*>(&row[tp0 + 512]) =
        make_float4(accE[0][jj] - accO[0][jj], accE[1][jj] - accO[1][jj],
                    accE[2][jj] - accO[2][jj], accE[3][jj] - accO[3][jj]);
  }
}

extern "C" void kernel_launch(void* const* d_in, const int* in_sizes, int n_in,
                              void* d_out, int out_size, void* d_ws, size_t ws_size,
                              hipStream_t stream) {
  const float* q   = (const float*)d_in[0];
  const float* k   = (const float*)d_in[1];
  // d_in[2] = value, unused by the reference forward
  const float* wre = (const float*)d_in[3];
  const float* wim = (const float*)d_in[4];
  float* out = (float*)d_out;
  float* ws  = (float*)d_ws;

  float* P   = ws;
  float* Pr  = ws + PR_OFF;
  float* C1c = ws + C1C_OFF;
  float* C2  = ws + C2_OFF;

  k_dft  <<<1024, 512, 0, stream>>>(q, k, P);
  k_red  <<<1024, 256, 0, stream>>>(P, Pr);
  k_mid_a<<<512,  512, 0, stream>>>(Pr, C1c);
  k_mid_b<<<4096,  64, 0, stream>>>(C1c, wre, wim, C2);
  k_idft <<<1024, 256, 0, stream>>>(C2, out);
}